// Round 1
// 3671.025 us; speedup vs baseline: 1.7938x; 1.7938x over previous
//
#include <hip/hip_runtime.h>
#include <math.h>

#define V_SZ   32000
#define D_SZ   768
#define H_N    12
#define KVH_N  4
#define L_N    6
#define T_SEQ  1024
#define HD_SZ  64
#define KVD_SZ 256
#define B_SZ   2
#define M_TOK  (B_SZ * T_SEQ)   // 2048 token rows

typedef unsigned int u32;
typedef unsigned short u16;
typedef float f32x4 __attribute__((ext_vector_type(4)));
typedef short bf16x8 __attribute__((ext_vector_type(8)));
typedef u32 u32x4 __attribute__((ext_vector_type(4)));

// ---------------- block-wide sum over 256 threads (4 waves) ----------------
__device__ __forceinline__ float block_reduce_sum_256(float v, float* ws4) {
#pragma unroll
  for (int o = 32; o; o >>= 1) v += __shfl_xor(v, o, 64);
  int wid = threadIdx.x >> 6;
  if ((threadIdx.x & 63) == 0) ws4[wid] = v;
  __syncthreads();
  return ws4[0] + ws4[1] + ws4[2] + ws4[3];
}

// ---------------- embedding + RMSNorm; writes x and x0 ----------------
__global__ __launch_bounds__(256) void embed_norm_k(
    const int* __restrict__ idx, const float* __restrict__ wte,
    float* __restrict__ x, float* __restrict__ x0) {
  __shared__ float ws4[4];
  int bt = blockIdx.x;
  int tok = idx[bt];
  const float* row = wte + (size_t)tok * D_SZ;
  float v[3]; float ss = 0.f;
#pragma unroll
  for (int i = 0; i < 3; i++) { v[i] = row[threadIdx.x + i * 256]; ss += v[i] * v[i]; }
  ss = block_reduce_sum_256(ss, ws4);
  float r = rsqrtf(ss * (1.f / D_SZ) + 1e-6f);
  size_t base = (size_t)bt * D_SZ + threadIdx.x;
#pragma unroll
  for (int i = 0; i < 3; i++) {
    float o = v[i] * r;
    x[base + i * 256] = o;
    x0[base + i * 256] = o;
  }
}

// -------- x = a*x + b*x0 (layer>=0) then xn = RMSNorm(x). layer<0: norm only --------
__global__ __launch_bounds__(256) void resid_norm_k(
    float* __restrict__ x, const float* __restrict__ x0, float* __restrict__ xn,
    const float* __restrict__ rl, const float* __restrict__ xl, int layer) {
  __shared__ float ws4[4];
  int bt = blockIdx.x;
  float a = 1.f, b = 0.f;
  if (layer >= 0) { a = rl[layer]; b = xl[layer]; }
  size_t base = (size_t)bt * D_SZ + threadIdx.x;
  float v[3]; float ss = 0.f;
#pragma unroll
  for (int i = 0; i < 3; i++) {
    float nv = a * x[base + i * 256] + b * x0[base + i * 256];
    v[i] = nv; ss += nv * nv;
    if (layer >= 0) x[base + i * 256] = nv;
  }
  ss = block_reduce_sum_256(ss, ws4);
  float r = rsqrtf(ss * (1.f / D_SZ) + 1e-6f);
#pragma unroll
  for (int i = 0; i < 3; i++) xn[base + i * 256] = v[i] * r;
}

// ---------------- RoPE + per-head RMSNorm for q (12 heads) and k (4 heads) ----------------
__global__ __launch_bounds__(64) void rope_norm_k(float* __restrict__ q, float* __restrict__ k) {
  int bt = blockIdx.x;
  int slot = blockIdx.y;
  int t = bt & (T_SEQ - 1);
  float* p;
  if (slot < H_N) p = q + (size_t)bt * D_SZ + slot * HD_SZ;
  else            p = k + (size_t)bt * KVD_SZ + (slot - H_N) * HD_SZ;
  int d = threadIdx.x;
  float self = p[d];
  float partner = p[d ^ 32];
  int j = d & 31;
  float inv = powf(10000.f, -(float)(2 * j) * (1.f / HD_SZ));
  float ang = (float)t * inv;
  float c = cosf(ang), s = sinf(ang);
  float out = (d < 32) ? (self * c + partner * s) : (self * c - partner * s);
  float ss = out * out;
#pragma unroll
  for (int o = 32; o; o >>= 1) ss += __shfl_xor(ss, o, 64);
  float r = rsqrtf(ss * (1.f / HD_SZ) + 1e-6f);
  p[d] = out * r;
}

// ---------------- value-embedding add ----------------
__global__ __launch_bounds__(256) void ve_add_k(
    float* __restrict__ v, const float* __restrict__ xn, const int* __restrict__ idx,
    const float* __restrict__ vt, const float* __restrict__ vg) {
  int bt = blockIdx.x;
  int kh = threadIdx.x >> 6;
  const float* xr = xn + (size_t)bt * D_SZ;
  const float* gr = vg + kh * 32;
  float dot = 0.f;
#pragma unroll
  for (int c = 0; c < 32; c++) dot += xr[c] * gr[c];
  float g = 2.f / (1.f + expf(-dot));
  int tok = idx[bt];
  v[(size_t)bt * KVD_SZ + threadIdx.x] += g * vt[(size_t)tok * KVD_SZ + threadIdx.x];
}

// ---------------- flash-style windowed-causal GQA attention (unchanged) ----------------
#define QT 32
#define KT 64
__global__ __launch_bounds__(256) void attn_k(
    const float* __restrict__ qg, const float* __restrict__ kg,
    const float* __restrict__ vg, float* __restrict__ yg, int window) {
  __shared__ float Qs[QT][HD_SZ + 1];
  __shared__ float Ks[KT][HD_SZ + 1];
  __shared__ float Vs[KT][HD_SZ];
  __shared__ float S[QT][KT + 1];
  __shared__ float m_s[QT], l_s[QT], alpha_s[QT];

  int qt0 = blockIdx.x * QT;
  int h   = blockIdx.y;
  int b   = blockIdx.z;
  int kh  = h / (H_N / KVH_N);
  int tid = threadIdx.x;

  for (int e = tid; e < QT * HD_SZ; e += 256) {
    int qi = e >> 6, d = e & 63;
    Qs[qi][d] = qg[(size_t)(b * T_SEQ + qt0 + qi) * D_SZ + h * HD_SZ + d] * 0.125f;
  }
  if (tid < QT) { m_s[tid] = -INFINITY; l_s[tid] = 0.f; }

  int gq = tid >> 4;
  int tx = tid & 15;
  int qi0 = gq * 2;
  float o_acc[2][4] = {{0,0,0,0},{0,0,0,0}};

  int klo = qt0 - window + 1; if (klo < 0) klo = 0;
  int khi = qt0 + QT - 1;
  int kt_start = klo & ~(KT - 1);

  for (int kt = kt_start; kt <= khi; kt += KT) {
    __syncthreads();
    for (int e = tid; e < KT * HD_SZ; e += 256) {
      int kj = e >> 6, d = e & 63;
      size_t gidx = (size_t)(b * T_SEQ + kt + kj) * KVD_SZ + kh * HD_SZ + d;
      Ks[kj][d] = kg[gidx];
      Vs[kj][d] = vg[gidx];
    }
    __syncthreads();

    int kj0 = tx * 4;
    float sc[2][4] = {{0,0,0,0},{0,0,0,0}};
    for (int d = 0; d < HD_SZ; d++) {
      float a0 = Qs[qi0][d], a1 = Qs[qi0 + 1][d];
      float b0 = Ks[kj0][d], b1 = Ks[kj0 + 1][d], b2 = Ks[kj0 + 2][d], b3 = Ks[kj0 + 3][d];
      sc[0][0] += a0 * b0; sc[0][1] += a0 * b1; sc[0][2] += a0 * b2; sc[0][3] += a0 * b3;
      sc[1][0] += a1 * b0; sc[1][1] += a1 * b1; sc[1][2] += a1 * b2; sc[1][3] += a1 * b3;
    }
#pragma unroll
    for (int r = 0; r < 2; r++) {
      int qpos = qt0 + qi0 + r;
#pragma unroll
      for (int j = 0; j < 4; j++) {
        int diff = qpos - (kt + kj0 + j);
        if (diff < 0 || diff >= window) sc[r][j] = -INFINITY;
      }
    }
#pragma unroll
    for (int r = 0; r < 2; r++) {
      int row = qi0 + r;
      float m = fmaxf(fmaxf(sc[r][0], sc[r][1]), fmaxf(sc[r][2], sc[r][3]));
#pragma unroll
      for (int o = 1; o < 16; o <<= 1) m = fmaxf(m, __shfl_xor(m, o, 64));
      float m_old = m_s[row];
      float m_new = fmaxf(m_old, m);
      float alpha, psum = 0.f;
      if (m_new == -INFINITY) {
        alpha = 1.f;
#pragma unroll
        for (int j = 0; j < 4; j++) S[row][kj0 + j] = 0.f;
      } else {
        alpha = expf(m_old - m_new);
#pragma unroll
        for (int j = 0; j < 4; j++) {
          float p = expf(sc[r][j] - m_new);
          S[row][kj0 + j] = p;
          psum += p;
        }
      }
#pragma unroll
      for (int o = 1; o < 16; o <<= 1) psum += __shfl_xor(psum, o, 64);
      if (tx == 0) {
        m_s[row] = m_new;
        alpha_s[row] = alpha;
        l_s[row] = alpha * l_s[row] + psum;
      }
    }
    __syncthreads();

    int d0 = tx * 4;
#pragma unroll
    for (int r = 0; r < 2; r++) {
      float al = alpha_s[qi0 + r];
#pragma unroll
      for (int c = 0; c < 4; c++) o_acc[r][c] *= al;
    }
    for (int kj = 0; kj < KT; kj++) {
      float p0 = S[qi0][kj], p1 = S[qi0 + 1][kj];
      float v0 = Vs[kj][d0], v1 = Vs[kj][d0 + 1], v2 = Vs[kj][d0 + 2], v3 = Vs[kj][d0 + 3];
      o_acc[0][0] += p0 * v0; o_acc[0][1] += p0 * v1; o_acc[0][2] += p0 * v2; o_acc[0][3] += p0 * v3;
      o_acc[1][0] += p1 * v0; o_acc[1][1] += p1 * v1; o_acc[1][2] += p1 * v2; o_acc[1][3] += p1 * v3;
    }
  }

  int d0 = tx * 4;
#pragma unroll
  for (int r = 0; r < 2; r++) {
    float inv_l = 1.f / l_s[qi0 + r];
    size_t yi = (size_t)(b * T_SEQ + qt0 + qi0 + r) * D_SZ + h * HD_SZ + d0;
    yg[yi + 0] = o_acc[r][0] * inv_l;
    yg[yi + 1] = o_acc[r][1] * inv_l;
    yg[yi + 2] = o_acc[r][2] * inv_l;
    yg[yi + 3] = o_acc[r][3] * inv_l;
  }
}

// ======================= split-bf16 (bf16x3) MFMA GEMM =======================
// Y[M][N] (op)= X[M][K] · W[N][K]^T, fp32 in HBM. Each fp32 a = a_hi + a_lo
// (bf16 each); a·b ≈ hi·hi + hi·lo + lo·hi via 3x mfma_f32_16x16x32_bf16.
// Tiles: BM x 128, BK=32. 256 threads = 4 waves (2x2). Conversion fp32->bf16
// happens in registers during staging; LDS holds bf16 tiles only.
// LDS fragment layout is k-chunked: [BK/8][rows][8] so each 16-lane group's
// ds_read_b128 is 256B contiguous -> conflict-free.
// EPI: 0 store, 1 Y+=acc, 2 relu(acc)^2, 3 15*tanh(acc/15)

__device__ __forceinline__ void split2(float a0, float a1, u32& hp, u32& lp) {
  u32 u0 = __float_as_uint(a0), u1 = __float_as_uint(a1);
  hp = (u0 >> 16) | (u1 & 0xffff0000u);          // hi = truncate-to-bf16
  float l0 = a0 - __uint_as_float(u0 & 0xffff0000u);
  float l1 = a1 - __uint_as_float(u1 & 0xffff0000u);
  u32 v0 = __float_as_uint(l0), v1 = __float_as_uint(l1);
  v0 += 0x7fffu + ((v0 >> 16) & 1u);             // lo = RNE-to-bf16
  v1 += 0x7fffu + ((v1 >> 16) & 1u);
  lp = (v0 >> 16) | (v1 & 0xffff0000u);
}

template <int BM, int EPI>
__global__ __launch_bounds__(256) void mfma_gemm_k(
    const float* __restrict__ X, const float* __restrict__ W, float* __restrict__ Y,
    int M, int N, int K) {
  constexpr int BN = 128;
  constexpr int BK = 32;
  constexpr int WM = BM / 2;          // wave tile rows (waves 2x2)
  constexpr int MR = WM / 16;         // m-fragments per wave
  constexpr int NR = 4;               // 64/16 n-fragments per wave
  constexpr int ACH = BM * (BK / 8);  // A 8-elem chunks per K-step
  constexpr int BCH = BN * (BK / 8);  // B chunks
  constexpr int TCH = ACH + BCH;
  constexpr int CPT = TCH / 256;      // chunks per thread
  static_assert(TCH % 256 == 0, "chunk count must divide evenly");
  static_assert(ACH % 256 == 0, "A/B chunk split must be wave-clean");

  __shared__ __align__(16) u16 sAh[ACH * 8], sAl[ACH * 8];
  __shared__ __align__(16) u16 sBh[BCH * 8], sBl[BCH * 8];

  const int tid  = threadIdx.x;
  const int lane = tid & 63;
  const int wave = tid >> 6;
  const int wr = wave >> 1, wc = wave & 1;
  const int l15 = lane & 15, l4 = lane >> 4;
  const int n0 = blockIdx.x * BN;
  const int m0 = blockIdx.y * BM;

  f32x4 acc[MR][NR];
#pragma unroll
  for (int mi = 0; mi < MR; mi++)
#pragma unroll
    for (int ni = 0; ni < NR; ni++) acc[mi][ni] = (f32x4){0.f, 0.f, 0.f, 0.f};

  // static chunk->thread mapping (i ranges are compile-time A or B blocks)
  const float* gsrc[CPT];
  int loff[CPT];
#pragma unroll
  for (int i = 0; i < CPT; i++) {
    int c = tid + i * 256;
    if ((i + 1) * 256 <= ACH) {
      int row = c >> 2, kc = c & 3;
      gsrc[i] = X + (size_t)(m0 + row) * K + kc * 8;
      loff[i] = (kc * BM + row) * 8;
    } else {
      int c2 = c - ACH;
      int row = c2 >> 2, kc = c2 & 3;
      gsrc[i] = W + (size_t)(n0 + row) * K + kc * 8;
      loff[i] = (kc * BN + row) * 8;
    }
  }

  float pre[CPT][8];
#pragma unroll
  for (int i = 0; i < CPT; i++) {
    *(float4*)&pre[i][0] = *(const float4*)(gsrc[i]);
    *(float4*)&pre[i][4] = *(const float4*)(gsrc[i] + 4);
  }

  const int nk = K / BK;
  for (int kt = 0; kt < nk; ++kt) {
    __syncthreads();                  // prev-iter LDS readers done
#pragma unroll
    for (int i = 0; i < CPT; i++) {
      u32 hp[4], lp[4];
#pragma unroll
      for (int j = 0; j < 4; j++)
        split2(pre[i][2 * j], pre[i][2 * j + 1], hp[j], lp[j]);
      bool ia = ((i + 1) * 256 <= ACH);   // folds at compile time
      u16* dh = ia ? sAh : sBh;
      u16* dl = ia ? sAl : sBl;
      *(u32x4*)(dh + loff[i]) = (u32x4){hp[0], hp[1], hp[2], hp[3]};
      *(u32x4*)(dl + loff[i]) = (u32x4){lp[0], lp[1], lp[2], lp[3]};
    }
    __syncthreads();

    // prefetch next K-step while MFMAs run
    if (kt + 1 < nk) {
#pragma unroll
      for (int i = 0; i < CPT; i++) {
        const float* p = gsrc[i] + (size_t)(kt + 1) * BK;
        *(float4*)&pre[i][0] = *(const float4*)(p);
        *(float4*)&pre[i][4] = *(const float4*)(p + 4);
      }
    }

    // fragments: lane l -> row (l&15), k = (l>>4)*8 + j  (contiguous 8)
    bf16x8 ah[MR], al[MR], bh[NR], bl[NR];
#pragma unroll
    for (int mi = 0; mi < MR; mi++) {
      int off = (l4 * BM + wr * WM + mi * 16 + l15) * 8;
      ah[mi] = *(const bf16x8*)(sAh + off);
      al[mi] = *(const bf16x8*)(sAl + off);
    }
#pragma unroll
    for (int ni = 0; ni < NR; ni++) {
      int off = (l4 * BN + wc * 64 + ni * 16 + l15) * 8;
      bh[ni] = *(const bf16x8*)(sBh + off);
      bl[ni] = *(const bf16x8*)(sBl + off);
    }
#pragma unroll
    for (int mi = 0; mi < MR; mi++)
#pragma unroll
      for (int ni = 0; ni < NR; ni++) {
        acc[mi][ni] = __builtin_amdgcn_mfma_f32_16x16x32_bf16(al[mi], bh[ni], acc[mi][ni], 0, 0, 0);
        acc[mi][ni] = __builtin_amdgcn_mfma_f32_16x16x32_bf16(ah[mi], bl[ni], acc[mi][ni], 0, 0, 0);
        acc[mi][ni] = __builtin_amdgcn_mfma_f32_16x16x32_bf16(ah[mi], bh[ni], acc[mi][ni], 0, 0, 0);
      }
  }

  // epilogue: D row = (l>>4)*4 + r, col = l&15 (m89-verified C/D layout)
#pragma unroll
  for (int mi = 0; mi < MR; mi++) {
#pragma unroll
    for (int r = 0; r < 4; r++) {
      int grow = m0 + wr * WM + mi * 16 + l4 * 4 + r;
      size_t rowoff = (size_t)grow * N;
#pragma unroll
      for (int ni = 0; ni < NR; ni++) {
        int gcol = n0 + wc * 64 + ni * 16 + l15;
        float v = acc[mi][ni][r];
        float* yp = Y + rowoff + gcol;
        if (EPI == 1) v += *yp;
        else if (EPI == 2) { v = fmaxf(v, 0.f); v *= v; }
        else if (EPI == 3) v = 15.f * tanhf(v * (1.f / 15.f));
        *yp = v;
      }
    }
  }
}

// ---------------- host-side launch ----------------
extern "C" void kernel_launch(void* const* d_in, const int* in_sizes, int n_in,
                              void* d_out, int out_size, void* d_ws, size_t ws_size,
                              hipStream_t stream) {
  (void)in_sizes; (void)n_in; (void)out_size; (void)ws_size;
  const int*   idx = (const int*)d_in[0];
  const float* wte = (const float*)d_in[1];
  const float* Wq  = (const float*)d_in[2];
  const float* Wk  = (const float*)d_in[3];
  const float* Wv  = (const float*)d_in[4];
  const float* Wo  = (const float*)d_in[5];
  const float* Wfc = (const float*)d_in[6];
  const float* Wpr = (const float*)d_in[7];
  const float* vet = (const float*)d_in[8];
  const float* veg = (const float*)d_in[9];
  const float* rl  = (const float*)d_in[10];
  const float* xl  = (const float*)d_in[11];
  const float* lmw = (const float*)d_in[12];
  float* out = (float*)d_out;

  float* ws = (float*)d_ws;
  float* x    = ws;                       // M_TOK * 768
  float* x0   = x  + (size_t)M_TOK * D_SZ;
  float* xn   = x0 + (size_t)M_TOK * D_SZ;
  float* q    = xn + (size_t)M_TOK * D_SZ;
  float* y    = q  + (size_t)M_TOK * D_SZ;
  float* kbuf = y  + (size_t)M_TOK * D_SZ;   // M_TOK * 256
  float* vbuf = kbuf + (size_t)M_TOK * KVD_SZ;
  float* hbuf = vbuf + (size_t)M_TOK * KVD_SZ;  // M_TOK * 3072

  const int windows[L_N] = {T_SEQ / 2, T_SEQ, T_SEQ / 2, T_SEQ, T_SEQ / 2, T_SEQ};
  const int ve_map[L_N]  = {-1, 0, -1, 1, -1, 2};

  embed_norm_k<<<M_TOK, 256, 0, stream>>>(idx, wte, x, x0);

  for (int i = 0; i < L_N; i++) {
    resid_norm_k<<<M_TOK, 256, 0, stream>>>(x, x0, xn, rl, xl, i);

    mfma_gemm_k<64, 0><<<dim3(D_SZ / 128, M_TOK / 64), 256, 0, stream>>>(
        xn, Wq + (size_t)i * D_SZ * D_SZ, q, M_TOK, D_SZ, D_SZ);
    mfma_gemm_k<64, 0><<<dim3(KVD_SZ / 128, M_TOK / 64), 256, 0, stream>>>(
        xn, Wk + (size_t)i * KVD_SZ * D_SZ, kbuf, M_TOK, KVD_SZ, D_SZ);
    mfma_gemm_k<64, 0><<<dim3(KVD_SZ / 128, M_TOK / 64), 256, 0, stream>>>(
        xn, Wv + (size_t)i * KVD_SZ * D_SZ, vbuf, M_TOK, KVD_SZ, D_SZ);

    if (ve_map[i] >= 0) {
      ve_add_k<<<M_TOK, 256, 0, stream>>>(
          vbuf, xn, idx, vet + (size_t)ve_map[i] * V_SZ * KVD_SZ,
          veg + (size_t)ve_map[i] * KVH_N * 32);
    }

    rope_norm_k<<<dim3(M_TOK, H_N + KVH_N), 64, 0, stream>>>(q, kbuf);

    attn_k<<<dim3(T_SEQ / QT, H_N, B_SZ), 256, 0, stream>>>(q, kbuf, vbuf, y, windows[i]);

    mfma_gemm_k<64, 1><<<dim3(D_SZ / 128, M_TOK / 64), 256, 0, stream>>>(
        y, Wo + (size_t)i * D_SZ * D_SZ, x, M_TOK, D_SZ, D_SZ);

    resid_norm_k<<<M_TOK, 256, 0, stream>>>(x, x0, xn, rl, xl, -1);

    mfma_gemm_k<128, 2><<<dim3(4 * D_SZ / 128, M_TOK / 128), 256, 0, stream>>>(
        xn, Wfc + (size_t)i * 4 * D_SZ * D_SZ, hbuf, M_TOK, 4 * D_SZ, D_SZ);

    mfma_gemm_k<64, 1><<<dim3(D_SZ / 128, M_TOK / 64), 256, 0, stream>>>(
        hbuf, Wpr + (size_t)i * D_SZ * 4 * D_SZ, x, M_TOK, D_SZ, 4 * D_SZ);
  }

  resid_norm_k<<<M_TOK, 256, 0, stream>>>(x, x0, xn, rl, xl, -1);
  mfma_gemm_k<128, 3><<<dim3(V_SZ / 128, M_TOK / 128), 256, 0, stream>>>(
      xn, lmw, out, M_TOK, V_SZ, D_SZ);
}

// Round 2
// 3181.872 us; speedup vs baseline: 2.0696x; 1.1537x over previous
//
#include <hip/hip_runtime.h>
#include <math.h>

#define V_SZ   32000
#define D_SZ   768
#define H_N    12
#define KVH_N  4
#define L_N    6
#define T_SEQ  1024
#define HD_SZ  64
#define KVD_SZ 256
#define B_SZ   2
#define M_TOK  (B_SZ * T_SEQ)   // 2048 token rows

typedef unsigned int u32;
typedef unsigned short u16;
typedef float f32x4 __attribute__((ext_vector_type(4)));
typedef short bf16x8 __attribute__((ext_vector_type(8)));
typedef u32 u32x4 __attribute__((ext_vector_type(4)));

// ---------------- fp32 -> bf16 hi/lo split (hi=trunc, lo=RNE of residual) ----------------
__device__ __forceinline__ void split2(float a0, float a1, u32& hp, u32& lp) {
  u32 u0 = __float_as_uint(a0), u1 = __float_as_uint(a1);
  hp = (u0 >> 16) | (u1 & 0xffff0000u);
  float l0 = a0 - __uint_as_float(u0 & 0xffff0000u);
  float l1 = a1 - __uint_as_float(u1 & 0xffff0000u);
  u32 v0 = __float_as_uint(l0), v1 = __float_as_uint(l1);
  v0 += 0x7fffu + ((v0 >> 16) & 1u);
  v1 += 0x7fffu + ((v1 >> 16) & 1u);
  lp = (v0 >> 16) | (v1 & 0xffff0000u);
}

__device__ __forceinline__ void split1(float a, u16& h, u16& l) {
  u32 u = __float_as_uint(a);
  h = (u16)(u >> 16);
  float lo = a - __uint_as_float(u & 0xffff0000u);
  u32 v = __float_as_uint(lo);
  v += 0x7fffu + ((v >> 16) & 1u);
  l = (u16)(v >> 16);
}

// ---------------- block-wide sum over 256 threads (4 waves) ----------------
__device__ __forceinline__ float block_reduce_sum_256(float v, float* ws4) {
#pragma unroll
  for (int o = 32; o; o >>= 1) v += __shfl_xor(v, o, 64);
  int wid = threadIdx.x >> 6;
  if ((threadIdx.x & 63) == 0) ws4[wid] = v;
  __syncthreads();
  return ws4[0] + ws4[1] + ws4[2] + ws4[3];
}

// ---------------- embedding + RMSNorm; writes x and x0 (fp32) ----------------
__global__ __launch_bounds__(256) void embed_norm_k(
    const int* __restrict__ idx, const float* __restrict__ wte,
    float* __restrict__ x, float* __restrict__ x0) {
  __shared__ float ws4[4];
  int bt = blockIdx.x;
  int tok = idx[bt];
  const float* row = wte + (size_t)tok * D_SZ;
  float v[3]; float ss = 0.f;
#pragma unroll
  for (int i = 0; i < 3; i++) { v[i] = row[threadIdx.x + i * 256]; ss += v[i] * v[i]; }
  ss = block_reduce_sum_256(ss, ws4);
  float r = rsqrtf(ss * (1.f / D_SZ) + 1e-6f);
  size_t base = (size_t)bt * D_SZ + threadIdx.x;
#pragma unroll
  for (int i = 0; i < 3; i++) {
    float o = v[i] * r;
    x[base + i * 256] = o;
    x0[base + i * 256] = o;
  }
}

// -------- x = a*x + b*x0 (layer>=0) then xn = RMSNorm(x), emitted SPLIT bf16 --------
// also writes xn32 (first 32 cols, fp32) for the ve gate.
__global__ __launch_bounds__(256) void resid_norm_k(
    float* __restrict__ x, const float* __restrict__ x0,
    u16* __restrict__ xnh, u16* __restrict__ xnl, float* __restrict__ xn32,
    const float* __restrict__ rl, const float* __restrict__ xl, int layer) {
  __shared__ float ws4[4];
  int bt = blockIdx.x;
  float a = 1.f, b = 0.f;
  if (layer >= 0) { a = rl[layer]; b = xl[layer]; }
  size_t base = (size_t)bt * D_SZ + threadIdx.x;
  float v[3]; float ss = 0.f;
#pragma unroll
  for (int i = 0; i < 3; i++) {
    float nv = a * x[base + i * 256] + b * x0[base + i * 256];
    v[i] = nv; ss += nv * nv;
    if (layer >= 0) x[base + i * 256] = nv;
  }
  ss = block_reduce_sum_256(ss, ws4);
  float r = rsqrtf(ss * (1.f / D_SZ) + 1e-6f);
#pragma unroll
  for (int i = 0; i < 3; i++) {
    float o = v[i] * r;
    u16 h, l; split1(o, h, l);
    xnh[base + i * 256] = h;
    xnl[base + i * 256] = l;
  }
  if (threadIdx.x < 32) xn32[(size_t)bt * 32 + threadIdx.x] = v[0] * r;
}

// ---------------- RoPE + per-head RMSNorm for q (12 heads) and k (4 heads) ----------------
__global__ __launch_bounds__(64) void rope_norm_k(float* __restrict__ q, float* __restrict__ k) {
  int bt = blockIdx.x;
  int slot = blockIdx.y;
  int t = bt & (T_SEQ - 1);
  float* p;
  if (slot < H_N) p = q + (size_t)bt * D_SZ + slot * HD_SZ;
  else            p = k + (size_t)bt * KVD_SZ + (slot - H_N) * HD_SZ;
  int d = threadIdx.x;
  float self = p[d];
  float partner = p[d ^ 32];
  int j = d & 31;
  float inv = powf(10000.f, -(float)(2 * j) * (1.f / HD_SZ));
  float ang = (float)t * inv;
  float c = cosf(ang), s = sinf(ang);
  float out = (d < 32) ? (self * c + partner * s) : (self * c - partner * s);
  float ss = out * out;
#pragma unroll
  for (int o = 32; o; o >>= 1) ss += __shfl_xor(ss, o, 64);
  float r = rsqrtf(ss * (1.f / HD_SZ) + 1e-6f);
  p[d] = out * r;
}

// ---------------- value-embedding add (gate from xn32) ----------------
__global__ __launch_bounds__(256) void ve_add_k(
    float* __restrict__ v, const float* __restrict__ xn32, const int* __restrict__ idx,
    const float* __restrict__ vt, const float* __restrict__ vg) {
  int bt = blockIdx.x;
  int kh = threadIdx.x >> 6;
  const float* xr = xn32 + (size_t)bt * 32;
  const float* gr = vg + kh * 32;
  float dot = 0.f;
#pragma unroll
  for (int c = 0; c < 32; c++) dot += xr[c] * gr[c];
  float g = 2.f / (1.f + expf(-dot));
  int tok = idx[bt];
  v[(size_t)bt * KVD_SZ + threadIdx.x] += g * vt[(size_t)tok * KVD_SZ + threadIdx.x];
}

// ---------------- flash-style windowed-causal GQA attention; split bf16 output ----------------
#define QT 32
#define KT 64
__global__ __launch_bounds__(256) void attn_k(
    const float* __restrict__ qg, const float* __restrict__ kg,
    const float* __restrict__ vg, u16* __restrict__ yh, u16* __restrict__ yl, int window) {
  __shared__ float Qs[QT][HD_SZ + 1];
  __shared__ float Ks[KT][HD_SZ + 1];
  __shared__ float Vs[KT][HD_SZ];
  __shared__ float S[QT][KT + 1];
  __shared__ float m_s[QT], l_s[QT], alpha_s[QT];

  int qt0 = blockIdx.x * QT;
  int h   = blockIdx.y;
  int b   = blockIdx.z;
  int kh  = h / (H_N / KVH_N);
  int tid = threadIdx.x;

  for (int e = tid; e < QT * HD_SZ; e += 256) {
    int qi = e >> 6, d = e & 63;
    Qs[qi][d] = qg[(size_t)(b * T_SEQ + qt0 + qi) * D_SZ + h * HD_SZ + d] * 0.125f;
  }
  if (tid < QT) { m_s[tid] = -INFINITY; l_s[tid] = 0.f; }

  int gq = tid >> 4;
  int tx = tid & 15;
  int qi0 = gq * 2;
  float o_acc[2][4] = {{0,0,0,0},{0,0,0,0}};

  int klo = qt0 - window + 1; if (klo < 0) klo = 0;
  int khi = qt0 + QT - 1;
  int kt_start = klo & ~(KT - 1);

  for (int kt = kt_start; kt <= khi; kt += KT) {
    __syncthreads();
    for (int e = tid; e < KT * HD_SZ; e += 256) {
      int kj = e >> 6, d = e & 63;
      size_t gidx = (size_t)(b * T_SEQ + kt + kj) * KVD_SZ + kh * HD_SZ + d;
      Ks[kj][d] = kg[gidx];
      Vs[kj][d] = vg[gidx];
    }
    __syncthreads();

    int kj0 = tx * 4;
    float sc[2][4] = {{0,0,0,0},{0,0,0,0}};
    for (int d = 0; d < HD_SZ; d++) {
      float a0 = Qs[qi0][d], a1 = Qs[qi0 + 1][d];
      float b0 = Ks[kj0][d], b1 = Ks[kj0 + 1][d], b2 = Ks[kj0 + 2][d], b3 = Ks[kj0 + 3][d];
      sc[0][0] += a0 * b0; sc[0][1] += a0 * b1; sc[0][2] += a0 * b2; sc[0][3] += a0 * b3;
      sc[1][0] += a1 * b0; sc[1][1] += a1 * b1; sc[1][2] += a1 * b2; sc[1][3] += a1 * b3;
    }
#pragma unroll
    for (int r = 0; r < 2; r++) {
      int qpos = qt0 + qi0 + r;
#pragma unroll
      for (int j = 0; j < 4; j++) {
        int diff = qpos - (kt + kj0 + j);
        if (diff < 0 || diff >= window) sc[r][j] = -INFINITY;
      }
    }
#pragma unroll
    for (int r = 0; r < 2; r++) {
      int row = qi0 + r;
      float m = fmaxf(fmaxf(sc[r][0], sc[r][1]), fmaxf(sc[r][2], sc[r][3]));
#pragma unroll
      for (int o = 1; o < 16; o <<= 1) m = fmaxf(m, __shfl_xor(m, o, 64));
      float m_old = m_s[row];
      float m_new = fmaxf(m_old, m);
      float alpha, psum = 0.f;
      if (m_new == -INFINITY) {
        alpha = 1.f;
#pragma unroll
        for (int j = 0; j < 4; j++) S[row][kj0 + j] = 0.f;
      } else {
        alpha = expf(m_old - m_new);
#pragma unroll
        for (int j = 0; j < 4; j++) {
          float p = expf(sc[r][j] - m_new);
          S[row][kj0 + j] = p;
          psum += p;
        }
      }
#pragma unroll
      for (int o = 1; o < 16; o <<= 1) psum += __shfl_xor(psum, o, 64);
      if (tx == 0) {
        m_s[row] = m_new;
        alpha_s[row] = alpha;
        l_s[row] = alpha * l_s[row] + psum;
      }
    }
    __syncthreads();

    int d0 = tx * 4;
#pragma unroll
    for (int r = 0; r < 2; r++) {
      float al = alpha_s[qi0 + r];
#pragma unroll
      for (int c = 0; c < 4; c++) o_acc[r][c] *= al;
    }
    for (int kj = 0; kj < KT; kj++) {
      float p0 = S[qi0][kj], p1 = S[qi0 + 1][kj];
      float v0 = Vs[kj][d0], v1 = Vs[kj][d0 + 1], v2 = Vs[kj][d0 + 2], v3 = Vs[kj][d0 + 3];
      o_acc[0][0] += p0 * v0; o_acc[0][1] += p0 * v1; o_acc[0][2] += p0 * v2; o_acc[0][3] += p0 * v3;
      o_acc[1][0] += p1 * v0; o_acc[1][1] += p1 * v1; o_acc[1][2] += p1 * v2; o_acc[1][3] += p1 * v3;
    }
  }

  int d0 = tx * 4;
#pragma unroll
  for (int r = 0; r < 2; r++) {
    float inv_l = 1.f / l_s[qi0 + r];
    size_t yi = (size_t)(b * T_SEQ + qt0 + qi0 + r) * D_SZ + h * HD_SZ + d0;
#pragma unroll
    for (int c = 0; c < 4; c++) {
      u16 hh_, ll_; split1(o_acc[r][c] * inv_l, hh_, ll_);
      yh[yi + c] = hh_;
      yl[yi + c] = ll_;
    }
  }
}

// ======================= split-bf16 (bf16x3) MFMA GEMM =======================
// A pre-split bf16 (Ah/Al, [M][K]); W fp32 [N][K], split in-kernel.
// LDS: row-major [rows][32] bf16 with granule XOR swizzle g=(row*4+kc)^(row&7)
// -> conflict-free writes AND fragment reads.
// EPI: 0 store fp32, 1 Y+=acc, 2 relu(acc)^2 -> split bf16 (Yth/Ytl), 3 softcap tanh

template <int BM, int EPI>
__device__ __forceinline__ void gemm_core(
    const u16* __restrict__ Ah, const u16* __restrict__ Al,
    const float* __restrict__ Wt,          // W + n0*K
    float* __restrict__ Yt,                // Y + n0
    u16* __restrict__ Yth, u16* __restrict__ Ytl,
    int ldY, int K, int m0) {
  constexpr int BN = 128;
  constexpr int BK = 32;
  constexpr int WM = BM / 2;
  constexpr int MR = WM / 16;
  constexpr int NR = 4;
  constexpr int AGT = BM * 4 / 256;   // A granules/thread (hi; lo same)
  constexpr int BGT = BN * 4 / 256;   // B chunks/thread
  static_assert(BM * 4 % 256 == 0, "");

  __shared__ __align__(16) u16 sAh[BM * 32], sAl[BM * 32];
  __shared__ __align__(16) u16 sBh[BN * 32], sBl[BN * 32];

  const int tid = threadIdx.x;
  const int lane = tid & 63, wave = tid >> 6;
  const int wr = wave >> 1, wc = wave & 1;
  const int l15 = lane & 15, l4 = lane >> 4;

  f32x4 acc[MR][NR];
#pragma unroll
  for (int mi = 0; mi < MR; mi++)
#pragma unroll
    for (int ni = 0; ni < NR; ni++) acc[mi][ni] = (f32x4){0.f, 0.f, 0.f, 0.f};

  const u16 *agh[AGT], *agl[AGT];
  int aoff[AGT];
#pragma unroll
  for (int i = 0; i < AGT; i++) {
    int c = tid + i * 256;
    int row = c >> 2, kc = c & 3;
    agh[i] = Ah + (size_t)(m0 + row) * K + kc * 8;
    agl[i] = Al + (size_t)(m0 + row) * K + kc * 8;
    aoff[i] = ((row * 4 + kc) ^ (row & 7)) * 8;
  }
  const float* bg[BGT];
  int boff[BGT];
#pragma unroll
  for (int i = 0; i < BGT; i++) {
    int c = tid + i * 256;
    int row = c >> 2, kc = c & 3;
    bg[i] = Wt + (size_t)row * K + kc * 8;
    boff[i] = ((row * 4 + kc) ^ (row & 7)) * 8;
  }

  u32x4 pAh[AGT], pAl[AGT];
  float pB[BGT][8];
#pragma unroll
  for (int i = 0; i < AGT; i++) { pAh[i] = *(const u32x4*)agh[i]; pAl[i] = *(const u32x4*)agl[i]; }
#pragma unroll
  for (int i = 0; i < BGT; i++) {
    *(float4*)&pB[i][0] = *(const float4*)bg[i];
    *(float4*)&pB[i][4] = *(const float4*)(bg[i] + 4);
  }

  const int nk = K / BK;
  for (int kt = 0; kt < nk; ++kt) {
    __syncthreads();
#pragma unroll
    for (int i = 0; i < AGT; i++) {
      *(u32x4*)(sAh + aoff[i]) = pAh[i];
      *(u32x4*)(sAl + aoff[i]) = pAl[i];
    }
#pragma unroll
    for (int i = 0; i < BGT; i++) {
      u32 hp[4], lp[4];
#pragma unroll
      for (int j = 0; j < 4; j++) split2(pB[i][2 * j], pB[i][2 * j + 1], hp[j], lp[j]);
      *(u32x4*)(sBh + boff[i]) = (u32x4){hp[0], hp[1], hp[2], hp[3]};
      *(u32x4*)(sBl + boff[i]) = (u32x4){lp[0], lp[1], lp[2], lp[3]};
    }
    __syncthreads();

    if (kt + 1 < nk) {
#pragma unroll
      for (int i = 0; i < AGT; i++) {
        pAh[i] = *(const u32x4*)(agh[i] + (size_t)(kt + 1) * BK);
        pAl[i] = *(const u32x4*)(agl[i] + (size_t)(kt + 1) * BK);
      }
#pragma unroll
      for (int i = 0; i < BGT; i++) {
        const float* p = bg[i] + (size_t)(kt + 1) * BK;
        *(float4*)&pB[i][0] = *(const float4*)p;
        *(float4*)&pB[i][4] = *(const float4*)(p + 4);
      }
    }

    bf16x8 fah[MR], fal[MR], fbh[NR], fbl[NR];
#pragma unroll
    for (int mi = 0; mi < MR; mi++) {
      int row = wr * WM + mi * 16 + l15;
      int off = ((row * 4 + l4) ^ (row & 7)) * 8;
      fah[mi] = *(const bf16x8*)(sAh + off);
      fal[mi] = *(const bf16x8*)(sAl + off);
    }
#pragma unroll
    for (int ni = 0; ni < NR; ni++) {
      int row = wc * 64 + ni * 16 + l15;
      int off = ((row * 4 + l4) ^ (row & 7)) * 8;
      fbh[ni] = *(const bf16x8*)(sBh + off);
      fbl[ni] = *(const bf16x8*)(sBl + off);
    }
#pragma unroll
    for (int mi = 0; mi < MR; mi++)
#pragma unroll
      for (int ni = 0; ni < NR; ni++) {
        acc[mi][ni] = __builtin_amdgcn_mfma_f32_16x16x32_bf16(fal[mi], fbh[ni], acc[mi][ni], 0, 0, 0);
        acc[mi][ni] = __builtin_amdgcn_mfma_f32_16x16x32_bf16(fah[mi], fbl[ni], acc[mi][ni], 0, 0, 0);
        acc[mi][ni] = __builtin_amdgcn_mfma_f32_16x16x32_bf16(fah[mi], fbh[ni], acc[mi][ni], 0, 0, 0);
      }
  }

  // epilogue: D row = (l>>4)*4 + r, col = l&15
#pragma unroll
  for (int mi = 0; mi < MR; mi++) {
#pragma unroll
    for (int r = 0; r < 4; r++) {
      int grow = m0 + wr * WM + mi * 16 + l4 * 4 + r;
      size_t rowoff = (size_t)grow * ldY;
#pragma unroll
      for (int ni = 0; ni < NR; ni++) {
        int col = wc * 64 + ni * 16 + l15;
        float v = acc[mi][ni][r];
        size_t oidx = rowoff + col;
        if (EPI == 0) {
          Yt[oidx] = v;
        } else if (EPI == 1) {
          Yt[oidx] += v;
        } else if (EPI == 2) {
          v = fmaxf(v, 0.f); v *= v;
          u16 h, l; split1(v, h, l);
          Yth[oidx] = h; Ytl[oidx] = l;
        } else {
          Yt[oidx] = 15.f * tanhf(v * (1.f / 15.f));
        }
      }
    }
  }
}

template <int BM, int EPI>
__global__ __launch_bounds__(256) void mfma_gemm_k(
    const u16* __restrict__ Ah, const u16* __restrict__ Al,
    const float* __restrict__ W, float* __restrict__ Y,
    u16* __restrict__ Yh, u16* __restrict__ Yl,
    int N, int K) {
  int n0 = blockIdx.x * 128;
  gemm_core<BM, EPI>(Ah, Al, W + (size_t)n0 * K,
                     Y ? Y + n0 : nullptr,
                     Yh ? Yh + n0 : nullptr, Yl ? Yl + n0 : nullptr,
                     N, K, blockIdx.y * BM);
}

// fused QKV: n-tiles 0..5 -> q, 6..7 -> k, 8..9 -> v
__global__ __launch_bounds__(256) void qkv_gemm_k(
    const u16* __restrict__ Ah, const u16* __restrict__ Al,
    const float* __restrict__ Wq, const float* __restrict__ Wk, const float* __restrict__ Wv,
    float* __restrict__ q, float* __restrict__ kb, float* __restrict__ vb) {
  int t = blockIdx.x;
  const float* W; float* Y; int ldY;
  if (t < 6)      { W = Wq + (size_t)t * 128 * D_SZ;       Y = q  + t * 128;       ldY = D_SZ; }
  else if (t < 8) { W = Wk + (size_t)(t - 6) * 128 * D_SZ; Y = kb + (t - 6) * 128; ldY = KVD_SZ; }
  else            { W = Wv + (size_t)(t - 8) * 128 * D_SZ; Y = vb + (t - 8) * 128; ldY = KVD_SZ; }
  gemm_core<64, 0>(Ah, Al, W, Y, nullptr, nullptr, ldY, D_SZ, blockIdx.y * 64);
}

// ---------------- host-side launch ----------------
extern "C" void kernel_launch(void* const* d_in, const int* in_sizes, int n_in,
                              void* d_out, int out_size, void* d_ws, size_t ws_size,
                              hipStream_t stream) {
  (void)in_sizes; (void)n_in; (void)out_size; (void)ws_size;
  const int*   idx = (const int*)d_in[0];
  const float* wte = (const float*)d_in[1];
  const float* Wq  = (const float*)d_in[2];
  const float* Wk  = (const float*)d_in[3];
  const float* Wv  = (const float*)d_in[4];
  const float* Wo  = (const float*)d_in[5];
  const float* Wfc = (const float*)d_in[6];
  const float* Wpr = (const float*)d_in[7];
  const float* vet = (const float*)d_in[8];
  const float* veg = (const float*)d_in[9];
  const float* rl  = (const float*)d_in[10];
  const float* xl  = (const float*)d_in[11];
  const float* lmw = (const float*)d_in[12];
  float* out = (float*)d_out;

  float* ws = (float*)d_ws;
  float* x    = ws;                                   // 2048*768 fp32
  float* x0   = x    + (size_t)M_TOK * D_SZ;
  float* q    = x0   + (size_t)M_TOK * D_SZ;
  float* kbuf = q    + (size_t)M_TOK * D_SZ;          // 2048*256
  float* vbuf = kbuf + (size_t)M_TOK * KVD_SZ;
  float* xn32 = vbuf + (size_t)M_TOK * KVD_SZ;        // 2048*32
  u16* xnh = (u16*)(xn32 + (size_t)M_TOK * 32);       // 2048*768 u16
  u16* xnl = xnh + (size_t)M_TOK * D_SZ;
  u16* hh  = xnl + (size_t)M_TOK * D_SZ;              // 2048*3072 u16
  u16* hl  = hh  + (size_t)M_TOK * 4 * D_SZ;
  u16* yh  = hh;   // alias: y dead before hh written
  u16* yl  = hl;

  const int windows[L_N] = {T_SEQ / 2, T_SEQ, T_SEQ / 2, T_SEQ, T_SEQ / 2, T_SEQ};
  const int ve_map[L_N]  = {-1, 0, -1, 1, -1, 2};

  embed_norm_k<<<M_TOK, 256, 0, stream>>>(idx, wte, x, x0);

  for (int i = 0; i < L_N; i++) {
    resid_norm_k<<<M_TOK, 256, 0, stream>>>(x, x0, xnh, xnl, xn32, rl, xl, i);

    qkv_gemm_k<<<dim3(10, M_TOK / 64), 256, 0, stream>>>(
        xnh, xnl,
        Wq + (size_t)i * D_SZ * D_SZ, Wk + (size_t)i * KVD_SZ * D_SZ,
        Wv + (size_t)i * KVD_SZ * D_SZ, q, kbuf, vbuf);

    if (ve_map[i] >= 0) {
      ve_add_k<<<M_TOK, 256, 0, stream>>>(
          vbuf, xn32, idx, vet + (size_t)ve_map[i] * V_SZ * KVD_SZ,
          veg + (size_t)ve_map[i] * KVH_N * 32);
    }

    rope_norm_k<<<dim3(M_TOK, H_N + KVH_N), 64, 0, stream>>>(q, kbuf);

    attn_k<<<dim3(T_SEQ / QT, H_N, B_SZ), 256, 0, stream>>>(q, kbuf, vbuf, yh, yl, windows[i]);

    mfma_gemm_k<64, 1><<<dim3(D_SZ / 128, M_TOK / 64), 256, 0, stream>>>(
        yh, yl, Wo + (size_t)i * D_SZ * D_SZ, x, nullptr, nullptr, D_SZ, D_SZ);

    resid_norm_k<<<M_TOK, 256, 0, stream>>>(x, x0, xnh, xnl, xn32, rl, xl, -1);

    mfma_gemm_k<128, 2><<<dim3(4 * D_SZ / 128, M_TOK / 128), 256, 0, stream>>>(
        xnh, xnl, Wfc + (size_t)i * 4 * D_SZ * D_SZ, nullptr, hh, hl, 4 * D_SZ, D_SZ);

    mfma_gemm_k<64, 1><<<dim3(D_SZ / 128, M_TOK / 64), 256, 0, stream>>>(
        hh, hl, Wpr + (size_t)i * D_SZ * 4 * D_SZ, x, nullptr, nullptr, D_SZ, 4 * D_SZ);
  }

  resid_norm_k<<<M_TOK, 256, 0, stream>>>(x, x0, xnh, xnl, xn32, rl, xl, -1);
  mfma_gemm_k<128, 3><<<dim3(V_SZ / 128, M_TOK / 128), 256, 0, stream>>>(
      xnh, xnl, lmw, out, nullptr, nullptr, V_SZ, D_SZ);
}